// Round 19
// baseline (220.726 us; speedup 1.0000x reference)
//
#include <hip/hip_runtime.h>
#include <hip/hip_bf16.h>

// Problem constants (fixed by setup_inputs)
constexpr int B_ = 8;
constexpr int H_ = 120;
constexpr int W_ = 160;
constexpr int N_ = H_ * W_;     // 19200
constexpr int C_ = 96;

constexpr int GX1 = 150;        // pass1 blocks per (s,b)
constexpr int TPB1 = 2;         // tiles of 64 rows per block (2400 blocks: 94% slot efficiency vs 78% at 1200)
constexpr int NT2 = N_ / 64;    // 300

typedef __attribute__((ext_vector_type(8))) short s16x8;
typedef __attribute__((ext_vector_type(4))) short s16x4;
typedef __attribute__((ext_vector_type(4))) float f32x4;

static __device__ inline unsigned short f2bf(float f) {
    unsigned u = __float_as_uint(f);
    return (unsigned short)((u + 0x7FFFu + ((u >> 16) & 1u)) >> 16);
}
static __device__ inline float bf2f(unsigned short h) {
    return __uint_as_float(((unsigned)h) << 16);
}
static __device__ inline void MFMA(f32x4& c, s16x8 a, s16x8 b) {
    c = __builtin_amdgcn_mfma_f32_16x16x32_bf16(a, b, c, 0, 0, 0);
}

// ---------------------------------------------------------------- prep: sincos table (6720) + W pre-pack (3456 frags)
// csS/snS layout: [0,2880): H-part (j*120+ih); [2880,6720): W-part (j*160+iw)
__global__ void prep_kernel(const float* __restrict__ Wqk, const float* __restrict__ Wv,
                            unsigned short* __restrict__ wpack,
                            float* __restrict__ csS, float* __restrict__ snS) {
    int idx = blockIdx.x * 256 + threadIdx.x;
    if (idx < 6720) {
        int j, pos;
        if (idx < 2880) { j = idx / 120; pos = idx - j * 120; }
        else { int t = idx - 2880; j = t / 160; pos = t - j * 160; }
        float theta = expf(-(float)j * (9.210340371976184f / 24.0f));
        float s, c;
        sincosf((float)pos * theta, &s, &c);
        csS[idx] = c;
        snS[idx] = s;
    } else if (idx < 6720 + 3456) {
        int i = idx - 6720;
        int s3 = i / 1152, rem = i - s3 * 1152;
        int cT = rem >> 6, lane = rem & 63;
        int col = cT * 16 + (lane & 15), k0 = s3 * 32 + 8 * (lane >> 4);
        const float* wp = (col < 192) ? (Wqk + col * 96 + k0) : (Wv + (col - 192) * 96 + k0);
        f32x4 wa = *(const f32x4*)wp;
        f32x4 wb = *(const f32x4*)(wp + 4);
        s16x8 wf;
        wf[0] = (short)f2bf(wa[0]); wf[1] = (short)f2bf(wa[1]);
        wf[2] = (short)f2bf(wa[2]); wf[3] = (short)f2bf(wa[3]);
        wf[4] = (short)f2bf(wb[0]); wf[5] = (short)f2bf(wb[1]);
        wf[6] = (short)f2bf(wb[2]); wf[7] = (short)f2bf(wb[3]);
        *(s16x8*)&wpack[i * 8] = wf;
    }
}

// ---------------------------------------------------------------- pass 1 (MFMA, fused shfl-rope, x prefetch, compact tables)
__global__ __launch_bounds__(256, 2)
void pass1_kernel(const float* __restrict__ x1, const float* __restrict__ x2,
                  const unsigned short* __restrict__ wpack,
                  const float* __restrict__ bqk, const float* __restrict__ bv,
                  const float* __restrict__ csS, const float* __restrict__ snS,
                  unsigned short* __restrict__ qbuf, unsigned short* __restrict__ vbuf,
                  float* __restrict__ kvpart, float* __restrict__ kmpart)
{
    __shared__ alignas(16) unsigned short Wl[27648];   // 55296 B, frag-order
    __shared__ alignas(16) unsigned short kTl[6144];   // 12288 B, frag-order [96ch][64r], ROPED k
    __shared__ alignas(16) unsigned short vTl[6144];   // 12288 B

    const int tid = threadIdx.x;
    const int l = tid & 63, w = tid >> 6;
    const int gx = blockIdx.x, b = blockIdx.y, s = blockIdx.z;
    const float* x = s ? x2 : x1;
    const int sb = s * B_ + b;

    // stage W from pre-packed global (coalesced, no conversion)
    for (int i = tid; i < 3456; i += 256)
        *(s16x8*)&Wl[i * 8] = *(const s16x8*)&wpack[i * 8];

    float biasv[18];
#pragma unroll
    for (int cT = 0; cT < 18; ++cT) {
        int col = cT * 16 + (l & 15);
        biasv[cT] = (col < 192) ? bqk[col] : bv[col - 192];
    }
    f32x4 kvacc[3] = {};
    float kmacc[6] = {};

    // x tile loader: 6 raw f32x4 (no conversion — keeps the prefetch pure loads)
    auto xload = [&](int n0t, f32x4* dst) {
        const float* xr = x + ((size_t)b * N_ + n0t + 16 * w + (l & 15)) * 96 + 8 * (l >> 4);
#pragma unroll
        for (int s3 = 0; s3 < 3; ++s3) {
            dst[2 * s3]     = *(const f32x4*)(xr + s3 * 32);
            dst[2 * s3 + 1] = *(const f32x4*)(xr + s3 * 32 + 4);
        }
    };
    f32x4 xcur[6], xnxt[6];
    xload(gx * TPB1 * 64, xcur);
    __syncthreads();

    for (int t = 0; t < TPB1; ++t) {
        const int n0 = (gx * TPB1 + t) * 64;
        const int r0 = 16 * w + 4 * (l >> 4);
        // prefetch next tile's x (lands during epilogue + kv-MFMA)
        if (t + 1 < TPB1) xload(n0 + 64, xnxt);
        // GEMM: wave w computes rows [16w,16w+16) x 288 cols
        f32x4 acc[18] = {};
#pragma unroll
        for (int s3 = 0; s3 < 3; ++s3) {
            f32x4 xa = xcur[2 * s3], xb = xcur[2 * s3 + 1];
            s16x8 af;
            af[0] = (short)f2bf(xa[0]); af[1] = (short)f2bf(xa[1]);
            af[2] = (short)f2bf(xa[2]); af[3] = (short)f2bf(xa[3]);
            af[4] = (short)f2bf(xb[0]); af[5] = (short)f2bf(xb[1]);
            af[6] = (short)f2bf(xb[2]); af[7] = (short)f2bf(xb[3]);
#pragma unroll
            for (int cT = 0; cT < 18; ++cT) {
                s16x8 bf = *(const s16x8*)&Wl[((s3 * 18 + cT) * 64 + l) * 8];
                MFMA(acc[cT], af, bf);
            }
        }
        // hoisted compact-table loads for THIS tile's k-epilogue.
        // rows nr..nr+3 never cross an image row (nr%4==0, 160%4==0): ih constant, iw0=nr%160
        const int nr = n0 + r0;
        const int ih = nr / 160, iw0 = nr - ih * 160;
        f32x4 c4a[6], s4a[6];
#pragma unroll
        for (int j6 = 0; j6 < 3; ++j6) {   // H-part: p = j6*8 + ((l&15)>>1) < 24, depends on ih only
            int p = j6 * 8 + ((l & 15) >> 1);
            float c = csS[p * 120 + ih], sv = snS[p * 120 + ih];
            c4a[j6][0] = c; c4a[j6][1] = c; c4a[j6][2] = c; c4a[j6][3] = c;
            s4a[j6][0] = sv; s4a[j6][1] = sv; s4a[j6][2] = sv; s4a[j6][3] = sv;
        }
#pragma unroll
        for (int j6 = 3; j6 < 6; ++j6) {   // W-part: p-24 = (j6-3)*8 + ((l&15)>>1), varies with iw
            int pw = (j6 - 3) * 8 + ((l & 15) >> 1);
            c4a[j6] = *(const f32x4*)&csS[2880 + pw * 160 + iw0];
            s4a[j6] = *(const f32x4*)&snS[2880 + pw * 160 + iw0];
        }
        __syncthreads();   // prev tile's kv-MFMA reads of kTl/vTl complete

        // ---- epilogue (rope fused via lane^1 shuffle)
        unsigned short* qb = qbuf + ((size_t)sb * N_ + n0) * 96;
        unsigned short* vb = vbuf + ((size_t)sb * N_ + n0) * 96;
#pragma unroll
        for (int cT = 0; cT < 6; ++cT) {          // q: elu+1, store pre-rope
#pragma unroll
            for (int i2 = 0; i2 < 4; ++i2) {
                float q = acc[cT][i2] + biasv[cT];
                q = (q > 0.f) ? q + 1.f : __expf(q);
                qb[(size_t)(r0 + i2) * 96 + cT * 16 + (l & 15)] = f2bf(q);
            }
        }
#pragma unroll
        for (int cT = 6; cT < 12; ++cT) {         // k: elu+1, kmean(pre-rope), rope, stage (b64)
            f32x4 c4 = c4a[cT - 6];
            f32x4 s4 = s4a[cT - 6];
            float colsum = 0.f;
            s16x4 pk;
#pragma unroll
            for (int i2 = 0; i2 < 4; ++i2) {
                float k = acc[cT][i2] + biasv[cT];
                k = (k > 0.f) ? k + 1.f : __expf(k);
                colsum += k;
                float kpart = __shfl_xor(k, 1, 64);   // partner channel (2p <-> 2p+1)
                float kr = (l & 1) ? fmaf(s4[i2], kpart, c4[i2] * k)     // odd: s*re + c*im
                                   : fmaf(-s4[i2], kpart, c4[i2] * k);   // even: c*re - s*im
                pk[i2] = (short)f2bf(kr);
            }
            int chunk = ((r0 >> 5) * 6 + (cT - 6)) * 64 + ((r0 >> 3) & 3) * 16 + (l & 15);
            *(s16x4*)&kTl[chunk * 8 + (r0 & 7)] = pk;
            colsum += __shfl_xor(colsum, 16, 64);
            colsum += __shfl_xor(colsum, 32, 64);
            kmacc[cT - 6] += colsum;
        }
#pragma unroll
        for (int cT = 12; cT < 18; ++cT) {        // v: store + stage to LDS (b64)
            s16x4 pv;
#pragma unroll
            for (int i2 = 0; i2 < 4; ++i2) {
                float v = acc[cT][i2] + biasv[cT];
                unsigned short hv = f2bf(v);
                pv[i2] = (short)hv;
                vb[(size_t)(r0 + i2) * 96 + (cT - 12) * 16 + (l & 15)] = hv;
            }
            int chunk = ((r0 >> 5) * 6 + (cT - 12)) * 64 + ((r0 >> 3) & 3) * 16 + (l & 15);
            *(s16x4*)&vTl[chunk * 8 + (r0 & 7)] = pv;
        }
        __syncthreads();
        // kv += k_roped^T @ v  (wave w owns flat C-tiles {w, w+4, w+8})
#pragma unroll
        for (int j = 0; j < 3; ++j) {
            int f = w + 4 * j;
            int h = f >> 2, dT = (f >> 1) & 1, eT = f & 1;
#pragma unroll
            for (int ks = 0; ks < 2; ++ks) {
                s16x8 a = *(const s16x8*)&kTl[(((ks * 6 + (h * 2 + dT)) << 6) + l) * 8];
                s16x8 bb = *(const s16x8*)&vTl[(((ks * 6 + (h * 2 + eT)) << 6) + l) * 8];
                MFMA(kvacc[j], a, bb);
            }
        }
        if (t + 1 < TPB1) {
#pragma unroll
            for (int i = 0; i < 6; ++i) xcur[i] = xnxt[i];
        }
    }
    // write partials
    float* kvp = kvpart + ((size_t)sb * GX1 + gx) * 3072;
#pragma unroll
    for (int j = 0; j < 3; ++j) {
        int f = w + 4 * j;
        int h = f >> 2, dT = (f >> 1) & 1, eT = f & 1;
#pragma unroll
        for (int i2 = 0; i2 < 4; ++i2)
            kvp[h * 1024 + (dT * 16 + 4 * (l >> 4) + i2) * 32 + eT * 16 + (l & 15)] = kvacc[j][i2];
    }
    if (l < 16) {
        float* kmp = kmpart + ((size_t)((size_t)sb * GX1 + gx) * 4 + w) * 96;
#pragma unroll
        for (int j6 = 0; j6 < 6; ++j6) kmp[j6 * 16 + l] = kmacc[j6];
    }
}

// ---------------------------------------------------------------- reduce (vectorized)
__global__ void reduce_kernel(const float* __restrict__ kvpart, const float* __restrict__ kmpart,
                              float* __restrict__ kvbuf, float* __restrict__ kmbuf)
{
    int idx = blockIdx.x * 256 + threadIdx.x;
    const float invN = 1.0f / (float)N_;
    if (idx < 16 * 768) {                       // kv: f32x4 chunks
        int sb = idx / 768, e4 = idx - sb * 768;
        f32x4 acc = {0.f, 0.f, 0.f, 0.f};
        for (int g = 0; g < GX1; ++g) {
            f32x4 vv = *(const f32x4*)&kvpart[((size_t)sb * GX1 + g) * 3072 + e4 * 4];
            acc[0] += vv[0]; acc[1] += vv[1]; acc[2] += vv[2]; acc[3] += vv[3];
        }
        acc[0] *= invN; acc[1] *= invN; acc[2] *= invN; acc[3] *= invN;
        *(f32x4*)&kvbuf[(size_t)sb * 3072 + e4 * 4] = acc;
    } else if (idx < 16 * 768 + 16 * 96) {
        int j = idx - 16 * 768;
        int sb = j / 96, ch = j - sb * 96;
        float acc = 0.f;
        for (int g = 0; g < GX1 * 4; ++g) acc += kmpart[((size_t)sb * GX1 * 4 + g) * 96 + ch];
        kmbuf[j] = acc * invN;
    }
}

// ---------------------------------------------------------------- pass 2 (direct-q frags, in-register rope, compact tables)
__global__ __launch_bounds__(256, 5)
void pass2_kernel(const unsigned short* __restrict__ qbuf, const unsigned short* __restrict__ vbuf,
                  const float* __restrict__ kvbuf, const float* __restrict__ kmbuf,
                  const float* __restrict__ csS, const float* __restrict__ snS,
                  const float* __restrict__ lw, const float* __restrict__ lb,
                  float* __restrict__ out)
{
    // aliased region: phase A = kvh (7680 B); phase B = osmT (25344 B)
    __shared__ alignas(16) char pbuf[25344];
    unsigned short* kvh = (unsigned short*)pbuf;             // [h*32+e][40]
    float* osmT = (float*)pbuf;                              // [96][66]
    __shared__ float zsh[192];
    __shared__ float lwL[864], lbL[96];

    const int tid = threadIdx.x, l = tid & 63, w = tid >> 6;
    // XCD-bijective tile swizzle (nwg=300: q=37, r=4) — contiguous tile runs per XCD for conv-halo L2 reuse
    const int orig = blockIdx.x;
    const int xcd = orig & 7, i8 = orig >> 3;
    const int tile = (xcd < 4 ? xcd * 38 : 152 + (xcd - 4) * 37) + i8;
    const int b = blockIdx.y, s = blockIdx.z, so = 1 - s;
    const int n0 = tile * 64;
    const int sb = s * B_ + b, sbo = so * B_ + b;

    // stage kv (bf16, transposed to [e][d])
    const float* kvsrc = kvbuf + (size_t)sbo * 3072;
    for (int i = tid; i < 3072; i += 256) {
        float vkv = kvsrc[i];
        int h = i >> 10, d = (i >> 5) & 31, e = i & 31;
        kvh[(h * 32 + e) * 40 + d] = f2bf(vkv);
    }
    for (int i = tid; i < 864; i += 256) lwL[i] = lw[i];
    if (tid < 96) lbL[tid] = lb[tid];

    // per-lane q fragment loads (direct from global)
    const int qrow = n0 + 16 * w + (l & 15);
    const int ihq = qrow / 160, iwq = qrow - ihq * 160;
    const unsigned short* qr = qbuf + ((size_t)sb * N_ + qrow) * 96 + 8 * (l >> 4);
    const float* kmp = kmbuf + (size_t)sbo * 96 + 8 * (l >> 4);
    s16x8 qf[3];
    float zv[3];
#pragma unroll
    for (int h = 0; h < 3; ++h) {
        qf[h] = *(const s16x8*)&qr[h * 32];
        f32x4 km0 = *(const f32x4*)&kmp[h * 32];
        f32x4 km1 = *(const f32x4*)&kmp[h * 32 + 4];
        float zp = 0.f;
#pragma unroll
        for (int e = 0; e < 4; ++e) zp += bf2f((unsigned short)qf[h][e]) * km0[e];
#pragma unroll
        for (int e = 0; e < 4; ++e) zp += bf2f((unsigned short)qf[h][4 + e]) * km1[e];
        zp += __shfl_xor(zp, 16, 64);
        zp += __shfl_xor(zp, 32, 64);
        zv[h] = zp;
    }
    if (l < 16) {
#pragma unroll
        for (int h = 0; h < 3; ++h)
            zsh[h * 64 + 16 * w + l] = 1.f / (zv[h] + 1e-6f);
    }
    // rope q in registers: pairs (2j,2j+1) within the lane's 8-elem chunk; compact table
    s16x8 af[3];
#pragma unroll
    for (int h = 0; h < 3; ++h) {
#pragma unroll
        for (int j = 0; j < 4; ++j) {
            int p = h * 16 + 4 * (l >> 4) + j;
            float c, sv;
            if (p < 24) { c = csS[p * 120 + ihq]; sv = snS[p * 120 + ihq]; }
            else { c = csS[2880 + (p - 24) * 160 + iwq]; sv = snS[2880 + (p - 24) * 160 + iwq]; }
            float re = bf2f((unsigned short)qf[h][2 * j]);
            float im = bf2f((unsigned short)qf[h][2 * j + 1]);
            af[h][2 * j]     = (short)f2bf(c * re - sv * im);
            af[h][2 * j + 1] = (short)f2bf(sv * re + c * im);
        }
    }
    __syncthreads();   // kvh + zsh ready
    // o = rope(q) @ kv
    f32x4 oac[3][2] = {};
#pragma unroll
    for (int h = 0; h < 3; ++h) {
#pragma unroll
        for (int eT = 0; eT < 2; ++eT) {
            int rowb = (h * 32 + eT * 16 + (l & 15)) * 40 + 8 * (l >> 4);
            MFMA(oac[h][eT], af[h], *(const s16x8*)&kvh[rowb]);
        }
    }
    __syncthreads();   // kvh reads done -> safe to overwrite as osmT
#pragma unroll
    for (int h = 0; h < 3; ++h) {
#pragma unroll
        for (int i2 = 0; i2 < 4; ++i2) {
            int row = 16 * w + 4 * (l >> 4) + i2;
            float z = zsh[h * 64 + row];
            osmT[(h * 32 + (l & 15)) * 66 + row] = oac[h][0][i2] * z;
            osmT[(h * 32 + 16 + (l & 15)) * 66 + row] = oac[h][1][i2] * z;
        }
    }
    __syncthreads();
    // LePE conv add: 768 ch-octets (64 r x 12 octets), ch-fast, u16x8 loads
    const unsigned short* vb = vbuf + (size_t)sb * (size_t)N_ * 96;
#pragma unroll
    for (int it = 0; it < 3; ++it) {
        int oct = it * 256 + tid;
        int r = oct / 12, c8 = oct - r * 12;
        int ch0 = c8 * 8;
        int npos = n0 + r, ih = npos / 160, iw = npos - ih * 160;
        float a[8];
#pragma unroll
        for (int e = 0; e < 8; ++e) a[e] = lbL[ch0 + e];
#pragma unroll
        for (int ky = 0; ky < 3; ++ky) {
            int ih2 = ih + ky - 1;
            if ((unsigned)ih2 >= 120u) continue;
#pragma unroll
            for (int kx = 0; kx < 3; ++kx) {
                int iw2 = iw + kx - 1;
                if ((unsigned)iw2 >= 160u) continue;
                s16x8 vv = *(const s16x8*)&vb[((size_t)ih2 * 160 + iw2) * 96 + ch0];
#pragma unroll
                for (int e = 0; e < 8; ++e)
                    a[e] = fmaf(bf2f((unsigned short)vv[e]), lwL[(ch0 + e) * 9 + ky * 3 + kx], a[e]);
            }
        }
#pragma unroll
        for (int e = 0; e < 8; ++e) osmT[(ch0 + e) * 66 + r] += a[e];
    }
    __syncthreads();
    // store transposed: out[sb][ch][n0+r], f32x4 over r
    float* ob = out + (size_t)sb * 96 * N_ + n0;
#pragma unroll
    for (int it = 0; it < 6; ++it) {
        int qq = it * 256 + tid;
        int r4 = (qq & 15) * 4, ch = qq >> 4;
        f32x4 vv;
        vv[0] = osmT[ch * 66 + r4];
        vv[1] = osmT[ch * 66 + r4 + 1];
        vv[2] = osmT[ch * 66 + r4 + 2];
        vv[3] = osmT[ch * 66 + r4 + 3];
        *(f32x4*)&ob[(size_t)ch * N_ + r4] = vv;
    }
}

// ---------------------------------------------------------------- launch
extern "C" void kernel_launch(void* const* d_in, const int* in_sizes, int n_in,
                              void* d_out, int out_size, void* d_ws, size_t ws_size,
                              hipStream_t stream)
{
    const float* x1  = (const float*)d_in[0];
    const float* x2  = (const float*)d_in[1];
    const float* Wqk = (const float*)d_in[2];
    const float* bqk = (const float*)d_in[3];
    const float* Wv  = (const float*)d_in[4];
    const float* bv  = (const float*)d_in[5];
    const float* lw  = (const float*)d_in[6];
    const float* lb  = (const float*)d_in[7];
    float* out = (float*)d_out;

    char* ws = (char*)d_ws;
    size_t off = 0;
    auto alloc = [&](size_t bytes) -> void* {
        void* p = ws + off;
        off = (off + bytes + 255) & ~(size_t)255;
        return p;
    };
    unsigned short* qbuf = (unsigned short*)alloc(2ull * B_ * N_ * 96 * 2);
    unsigned short* vbuf = (unsigned short*)alloc(2ull * B_ * N_ * 96 * 2);
    float* kvpart = (float*)alloc(16ull * GX1 * 3072 * 4);
    float* kmpart = (float*)alloc(16ull * GX1 * 4 * 96 * 4);
    float* kvbuf  = (float*)alloc(16ull * 3072 * 4);
    float* kmbuf  = (float*)alloc(16ull * 96 * 4);
    unsigned short* wpack = (unsigned short*)alloc(3456ull * 8 * 2);
    float* csS = (float*)alloc(6720 * 4);
    float* snS = (float*)alloc(6720 * 4);

    hipLaunchKernelGGL(prep_kernel, dim3((6720 + 3456 + 255) / 256), dim3(256), 0, stream,
                       Wqk, Wv, wpack, csS, snS);
    hipLaunchKernelGGL(pass1_kernel, dim3(GX1, B_, 2), dim3(256), 0, stream,
                       x1, x2, wpack, bqk, bv, csS, snS, qbuf, vbuf, kvpart, kmpart);
    hipLaunchKernelGGL(reduce_kernel, dim3((16 * 768 + 16 * 96 + 255) / 256), dim3(256), 0, stream,
                       kvpart, kmpart, kvbuf, kmbuf);
    hipLaunchKernelGGL(pass2_kernel, dim3(NT2, B_, 2), dim3(256), 0, stream,
                       qbuf, vbuf, kvbuf, kmbuf, csS, snS, lw, lb, out);
}

// Round 20
// 200.880 us; speedup vs baseline: 1.0988x; 1.0988x over previous
//
#include <hip/hip_runtime.h>
#include <hip/hip_bf16.h>

// Problem constants (fixed by setup_inputs)
constexpr int B_ = 8;
constexpr int H_ = 120;
constexpr int W_ = 160;
constexpr int N_ = H_ * W_;     // 19200
constexpr int C_ = 96;

constexpr int GX1 = 75;         // pass1 blocks per (s,b)
constexpr int TPB1 = 4;         // tiles of 64 rows per block
constexpr int NT2 = N_ / 64;    // 300

typedef __attribute__((ext_vector_type(8))) short s16x8;
typedef __attribute__((ext_vector_type(4))) short s16x4;
typedef __attribute__((ext_vector_type(4))) float f32x4;

static __device__ inline unsigned short f2bf(float f) {
    unsigned u = __float_as_uint(f);
    return (unsigned short)((u + 0x7FFFu + ((u >> 16) & 1u)) >> 16);
}
static __device__ inline float bf2f(unsigned short h) {
    return __uint_as_float(((unsigned)h) << 16);
}
static __device__ inline void MFMA(f32x4& c, s16x8 a, s16x8 b) {
    c = __builtin_amdgcn_mfma_f32_16x16x32_bf16(a, b, c, 0, 0, 0);
}

// ---------------------------------------------------------------- prep: sincos table (6720) + W pre-pack (3456 frags)
// csS/snS layout: [0,2880): H-part (j*120+ih); [2880,6720): W-part (j*160+iw)
__global__ void prep_kernel(const float* __restrict__ Wqk, const float* __restrict__ Wv,
                            unsigned short* __restrict__ wpack,
                            float* __restrict__ csS, float* __restrict__ snS) {
    int idx = blockIdx.x * 256 + threadIdx.x;
    if (idx < 6720) {
        int j, pos;
        if (idx < 2880) { j = idx / 120; pos = idx - j * 120; }
        else { int t = idx - 2880; j = t / 160; pos = t - j * 160; }
        float theta = expf(-(float)j * (9.210340371976184f / 24.0f));
        float s, c;
        sincosf((float)pos * theta, &s, &c);
        csS[idx] = c;
        snS[idx] = s;
    } else if (idx < 6720 + 3456) {
        int i = idx - 6720;
        int s3 = i / 1152, rem = i - s3 * 1152;
        int cT = rem >> 6, lane = rem & 63;
        int col = cT * 16 + (lane & 15), k0 = s3 * 32 + 8 * (lane >> 4);
        const float* wp = (col < 192) ? (Wqk + col * 96 + k0) : (Wv + (col - 192) * 96 + k0);
        f32x4 wa = *(const f32x4*)wp;
        f32x4 wb = *(const f32x4*)(wp + 4);
        s16x8 wf;
        wf[0] = (short)f2bf(wa[0]); wf[1] = (short)f2bf(wa[1]);
        wf[2] = (short)f2bf(wa[2]); wf[3] = (short)f2bf(wa[3]);
        wf[4] = (short)f2bf(wb[0]); wf[5] = (short)f2bf(wb[1]);
        wf[6] = (short)f2bf(wb[2]); wf[7] = (short)f2bf(wb[3]);
        *(s16x8*)&wpack[i * 8] = wf;
    }
}

// ---------------------------------------------------------------- pass 1 (MFMA, fused shfl-rope, x prefetch, compact tables)
__global__ __launch_bounds__(256, 2)
void pass1_kernel(const float* __restrict__ x1, const float* __restrict__ x2,
                  const unsigned short* __restrict__ wpack,
                  const float* __restrict__ bqk, const float* __restrict__ bv,
                  const float* __restrict__ csS, const float* __restrict__ snS,
                  unsigned short* __restrict__ qbuf, unsigned short* __restrict__ vbuf,
                  float* __restrict__ kvpart, float* __restrict__ kmpart)
{
    __shared__ alignas(16) unsigned short Wl[27648];   // 55296 B, frag-order
    __shared__ alignas(16) unsigned short kTl[6144];   // 12288 B, frag-order [96ch][64r], ROPED k
    __shared__ alignas(16) unsigned short vTl[6144];   // 12288 B

    const int tid = threadIdx.x;
    const int l = tid & 63, w = tid >> 6;
    const int gx = blockIdx.x, b = blockIdx.y, s = blockIdx.z;
    const float* x = s ? x2 : x1;
    const int sb = s * B_ + b;

    // stage W from pre-packed global (coalesced, no conversion)
    for (int i = tid; i < 3456; i += 256)
        *(s16x8*)&Wl[i * 8] = *(const s16x8*)&wpack[i * 8];

    float biasv[18];
#pragma unroll
    for (int cT = 0; cT < 18; ++cT) {
        int col = cT * 16 + (l & 15);
        biasv[cT] = (col < 192) ? bqk[col] : bv[col - 192];
    }
    f32x4 kvacc[3] = {};
    float kmacc[6] = {};

    // x tile loader: 6 raw f32x4 (no conversion — keeps the prefetch pure loads)
    auto xload = [&](int n0t, f32x4* dst) {
        const float* xr = x + ((size_t)b * N_ + n0t + 16 * w + (l & 15)) * 96 + 8 * (l >> 4);
#pragma unroll
        for (int s3 = 0; s3 < 3; ++s3) {
            dst[2 * s3]     = *(const f32x4*)(xr + s3 * 32);
            dst[2 * s3 + 1] = *(const f32x4*)(xr + s3 * 32 + 4);
        }
    };
    f32x4 xcur[6], xnxt[6];
    xload(gx * TPB1 * 64, xcur);
    __syncthreads();

    for (int t = 0; t < TPB1; ++t) {
        const int n0 = (gx * TPB1 + t) * 64;
        const int r0 = 16 * w + 4 * (l >> 4);
        // prefetch next tile's x (lands during epilogue + kv-MFMA)
        if (t + 1 < TPB1) xload(n0 + 64, xnxt);
        // GEMM: wave w computes rows [16w,16w+16) x 288 cols
        f32x4 acc[18] = {};
#pragma unroll
        for (int s3 = 0; s3 < 3; ++s3) {
            f32x4 xa = xcur[2 * s3], xb = xcur[2 * s3 + 1];
            s16x8 af;
            af[0] = (short)f2bf(xa[0]); af[1] = (short)f2bf(xa[1]);
            af[2] = (short)f2bf(xa[2]); af[3] = (short)f2bf(xa[3]);
            af[4] = (short)f2bf(xb[0]); af[5] = (short)f2bf(xb[1]);
            af[6] = (short)f2bf(xb[2]); af[7] = (short)f2bf(xb[3]);
#pragma unroll
            for (int cT = 0; cT < 18; ++cT) {
                s16x8 bf = *(const s16x8*)&Wl[((s3 * 18 + cT) * 64 + l) * 8];
                MFMA(acc[cT], af, bf);
            }
        }
        // hoisted compact-table loads for THIS tile's k-epilogue.
        // rows nr..nr+3 never cross an image row (nr%4==0, 160%4==0): ih constant, iw0=nr%160
        const int nr = n0 + r0;
        const int ih = nr / 160, iw0 = nr - ih * 160;
        f32x4 c4a[6], s4a[6];
#pragma unroll
        for (int j6 = 0; j6 < 3; ++j6) {   // H-part: p = j6*8 + ((l&15)>>1) < 24, depends on ih only
            int p = j6 * 8 + ((l & 15) >> 1);
            float c = csS[p * 120 + ih], sv = snS[p * 120 + ih];
            c4a[j6][0] = c; c4a[j6][1] = c; c4a[j6][2] = c; c4a[j6][3] = c;
            s4a[j6][0] = sv; s4a[j6][1] = sv; s4a[j6][2] = sv; s4a[j6][3] = sv;
        }
#pragma unroll
        for (int j6 = 3; j6 < 6; ++j6) {   // W-part: p-24 = (j6-3)*8 + ((l&15)>>1), varies with iw
            int pw = (j6 - 3) * 8 + ((l & 15) >> 1);
            c4a[j6] = *(const f32x4*)&csS[2880 + pw * 160 + iw0];
            s4a[j6] = *(const f32x4*)&snS[2880 + pw * 160 + iw0];
        }
        __syncthreads();   // prev tile's kv-MFMA reads of kTl/vTl complete

        // ---- epilogue (rope fused via lane^1 shuffle)
        unsigned short* qb = qbuf + ((size_t)sb * N_ + n0) * 96;
        unsigned short* vb = vbuf + ((size_t)sb * N_ + n0) * 96;
#pragma unroll
        for (int cT = 0; cT < 6; ++cT) {          // q: elu+1, store pre-rope
#pragma unroll
            for (int i2 = 0; i2 < 4; ++i2) {
                float q = acc[cT][i2] + biasv[cT];
                q = (q > 0.f) ? q + 1.f : __expf(q);
                qb[(size_t)(r0 + i2) * 96 + cT * 16 + (l & 15)] = f2bf(q);
            }
        }
#pragma unroll
        for (int cT = 6; cT < 12; ++cT) {         // k: elu+1, kmean(pre-rope), rope, stage (b64)
            f32x4 c4 = c4a[cT - 6];
            f32x4 s4 = s4a[cT - 6];
            float colsum = 0.f;
            s16x4 pk;
#pragma unroll
            for (int i2 = 0; i2 < 4; ++i2) {
                float k = acc[cT][i2] + biasv[cT];
                k = (k > 0.f) ? k + 1.f : __expf(k);
                colsum += k;
                float kpart = __shfl_xor(k, 1, 64);   // partner channel (2p <-> 2p+1)
                float kr = (l & 1) ? fmaf(s4[i2], kpart, c4[i2] * k)     // odd: s*re + c*im
                                   : fmaf(-s4[i2], kpart, c4[i2] * k);   // even: c*re - s*im
                pk[i2] = (short)f2bf(kr);
            }
            int chunk = ((r0 >> 5) * 6 + (cT - 6)) * 64 + ((r0 >> 3) & 3) * 16 + (l & 15);
            *(s16x4*)&kTl[chunk * 8 + (r0 & 7)] = pk;
            colsum += __shfl_xor(colsum, 16, 64);
            colsum += __shfl_xor(colsum, 32, 64);
            kmacc[cT - 6] += colsum;
        }
#pragma unroll
        for (int cT = 12; cT < 18; ++cT) {        // v: store + stage to LDS (b64)
            s16x4 pv;
#pragma unroll
            for (int i2 = 0; i2 < 4; ++i2) {
                float v = acc[cT][i2] + biasv[cT];
                unsigned short hv = f2bf(v);
                pv[i2] = (short)hv;
                vb[(size_t)(r0 + i2) * 96 + (cT - 12) * 16 + (l & 15)] = hv;
            }
            int chunk = ((r0 >> 5) * 6 + (cT - 12)) * 64 + ((r0 >> 3) & 3) * 16 + (l & 15);
            *(s16x4*)&vTl[chunk * 8 + (r0 & 7)] = pv;
        }
        __syncthreads();
        // kv += k_roped^T @ v  (wave w owns flat C-tiles {w, w+4, w+8})
#pragma unroll
        for (int j = 0; j < 3; ++j) {
            int f = w + 4 * j;
            int h = f >> 2, dT = (f >> 1) & 1, eT = f & 1;
#pragma unroll
            for (int ks = 0; ks < 2; ++ks) {
                s16x8 a = *(const s16x8*)&kTl[(((ks * 6 + (h * 2 + dT)) << 6) + l) * 8];
                s16x8 bb = *(const s16x8*)&vTl[(((ks * 6 + (h * 2 + eT)) << 6) + l) * 8];
                MFMA(kvacc[j], a, bb);
            }
        }
        if (t + 1 < TPB1) {
#pragma unroll
            for (int i = 0; i < 6; ++i) xcur[i] = xnxt[i];
        }
    }
    // write partials
    float* kvp = kvpart + ((size_t)sb * GX1 + gx) * 3072;
#pragma unroll
    for (int j = 0; j < 3; ++j) {
        int f = w + 4 * j;
        int h = f >> 2, dT = (f >> 1) & 1, eT = f & 1;
#pragma unroll
        for (int i2 = 0; i2 < 4; ++i2)
            kvp[h * 1024 + (dT * 16 + 4 * (l >> 4) + i2) * 32 + eT * 16 + (l & 15)] = kvacc[j][i2];
    }
    if (l < 16) {
        float* kmp = kmpart + ((size_t)((size_t)sb * GX1 + gx) * 4 + w) * 96;
#pragma unroll
        for (int j6 = 0; j6 < 6; ++j6) kmp[j6 * 16 + l] = kmacc[j6];
    }
}

// ---------------------------------------------------------------- reduce (vectorized)
__global__ void reduce_kernel(const float* __restrict__ kvpart, const float* __restrict__ kmpart,
                              float* __restrict__ kvbuf, float* __restrict__ kmbuf)
{
    int idx = blockIdx.x * 256 + threadIdx.x;
    const float invN = 1.0f / (float)N_;
    if (idx < 16 * 768) {                       // kv: f32x4 chunks
        int sb = idx / 768, e4 = idx - sb * 768;
        f32x4 acc = {0.f, 0.f, 0.f, 0.f};
        for (int g = 0; g < GX1; ++g) {
            f32x4 vv = *(const f32x4*)&kvpart[((size_t)sb * GX1 + g) * 3072 + e4 * 4];
            acc[0] += vv[0]; acc[1] += vv[1]; acc[2] += vv[2]; acc[3] += vv[3];
        }
        acc[0] *= invN; acc[1] *= invN; acc[2] *= invN; acc[3] *= invN;
        *(f32x4*)&kvbuf[(size_t)sb * 3072 + e4 * 4] = acc;
    } else if (idx < 16 * 768 + 16 * 96) {
        int j = idx - 16 * 768;
        int sb = j / 96, ch = j - sb * 96;
        float acc = 0.f;
        for (int g = 0; g < GX1 * 4; ++g) acc += kmpart[((size_t)sb * GX1 * 4 + g) * 96 + ch];
        kmbuf[j] = acc * invN;
    }
}

// ---------------------------------------------------------------- pass 2 (direct-q frags, in-register rope, compact tables)
__global__ __launch_bounds__(256, 5)
void pass2_kernel(const unsigned short* __restrict__ qbuf, const unsigned short* __restrict__ vbuf,
                  const float* __restrict__ kvbuf, const float* __restrict__ kmbuf,
                  const float* __restrict__ csS, const float* __restrict__ snS,
                  const float* __restrict__ lw, const float* __restrict__ lb,
                  float* __restrict__ out)
{
    // aliased region: phase A = kvh (7680 B); phase B = osmT (25344 B)
    __shared__ alignas(16) char pbuf[25344];
    unsigned short* kvh = (unsigned short*)pbuf;             // [h*32+e][40]
    float* osmT = (float*)pbuf;                              // [96][66]
    __shared__ float zsh[192];
    __shared__ float lwL[864], lbL[96];

    const int tid = threadIdx.x, l = tid & 63, w = tid >> 6;
    // XCD-bijective tile swizzle (nwg=300: q=37, r=4) — contiguous tile runs per XCD for conv-halo L2 reuse
    const int orig = blockIdx.x;
    const int xcd = orig & 7, i8 = orig >> 3;
    const int tile = (xcd < 4 ? xcd * 38 : 152 + (xcd - 4) * 37) + i8;
    const int b = blockIdx.y, s = blockIdx.z, so = 1 - s;
    const int n0 = tile * 64;
    const int sb = s * B_ + b, sbo = so * B_ + b;

    // stage kv (bf16, transposed to [e][d])
    const float* kvsrc = kvbuf + (size_t)sbo * 3072;
    for (int i = tid; i < 3072; i += 256) {
        float vkv = kvsrc[i];
        int h = i >> 10, d = (i >> 5) & 31, e = i & 31;
        kvh[(h * 32 + e) * 40 + d] = f2bf(vkv);
    }
    for (int i = tid; i < 864; i += 256) lwL[i] = lw[i];
    if (tid < 96) lbL[tid] = lb[tid];

    // per-lane q fragment loads (direct from global)
    const int qrow = n0 + 16 * w + (l & 15);
    const int ihq = qrow / 160, iwq = qrow - ihq * 160;
    const unsigned short* qr = qbuf + ((size_t)sb * N_ + qrow) * 96 + 8 * (l >> 4);
    const float* kmp = kmbuf + (size_t)sbo * 96 + 8 * (l >> 4);
    s16x8 qf[3];
    float zv[3];
#pragma unroll
    for (int h = 0; h < 3; ++h) {
        qf[h] = *(const s16x8*)&qr[h * 32];
        f32x4 km0 = *(const f32x4*)&kmp[h * 32];
        f32x4 km1 = *(const f32x4*)&kmp[h * 32 + 4];
        float zp = 0.f;
#pragma unroll
        for (int e = 0; e < 4; ++e) zp += bf2f((unsigned short)qf[h][e]) * km0[e];
#pragma unroll
        for (int e = 0; e < 4; ++e) zp += bf2f((unsigned short)qf[h][4 + e]) * km1[e];
        zp += __shfl_xor(zp, 16, 64);
        zp += __shfl_xor(zp, 32, 64);
        zv[h] = zp;
    }
    if (l < 16) {
#pragma unroll
        for (int h = 0; h < 3; ++h)
            zsh[h * 64 + 16 * w + l] = 1.f / (zv[h] + 1e-6f);
    }
    // rope q in registers: pairs (2j,2j+1) within the lane's 8-elem chunk; compact table
    s16x8 af[3];
#pragma unroll
    for (int h = 0; h < 3; ++h) {
#pragma unroll
        for (int j = 0; j < 4; ++j) {
            int p = h * 16 + 4 * (l >> 4) + j;
            float c, sv;
            if (p < 24) { c = csS[p * 120 + ihq]; sv = snS[p * 120 + ihq]; }
            else { c = csS[2880 + (p - 24) * 160 + iwq]; sv = snS[2880 + (p - 24) * 160 + iwq]; }
            float re = bf2f((unsigned short)qf[h][2 * j]);
            float im = bf2f((unsigned short)qf[h][2 * j + 1]);
            af[h][2 * j]     = (short)f2bf(c * re - sv * im);
            af[h][2 * j + 1] = (short)f2bf(sv * re + c * im);
        }
    }
    __syncthreads();   // kvh + zsh ready
    // o = rope(q) @ kv
    f32x4 oac[3][2] = {};
#pragma unroll
    for (int h = 0; h < 3; ++h) {
#pragma unroll
        for (int eT = 0; eT < 2; ++eT) {
            int rowb = (h * 32 + eT * 16 + (l & 15)) * 40 + 8 * (l >> 4);
            MFMA(oac[h][eT], af[h], *(const s16x8*)&kvh[rowb]);
        }
    }
    __syncthreads();   // kvh reads done -> safe to overwrite as osmT
#pragma unroll
    for (int h = 0; h < 3; ++h) {
#pragma unroll
        for (int i2 = 0; i2 < 4; ++i2) {
            int row = 16 * w + 4 * (l >> 4) + i2;
            float z = zsh[h * 64 + row];
            osmT[(h * 32 + (l & 15)) * 66 + row] = oac[h][0][i2] * z;
            osmT[(h * 32 + 16 + (l & 15)) * 66 + row] = oac[h][1][i2] * z;
        }
    }
    __syncthreads();
    // LePE conv add: 768 ch-octets (64 r x 12 octets), ch-fast, u16x8 loads
    const unsigned short* vb = vbuf + (size_t)sb * (size_t)N_ * 96;
#pragma unroll
    for (int it = 0; it < 3; ++it) {
        int oct = it * 256 + tid;
        int r = oct / 12, c8 = oct - r * 12;
        int ch0 = c8 * 8;
        int npos = n0 + r, ih = npos / 160, iw = npos - ih * 160;
        float a[8];
#pragma unroll
        for (int e = 0; e < 8; ++e) a[e] = lbL[ch0 + e];
#pragma unroll
        for (int ky = 0; ky < 3; ++ky) {
            int ih2 = ih + ky - 1;
            if ((unsigned)ih2 >= 120u) continue;
#pragma unroll
            for (int kx = 0; kx < 3; ++kx) {
                int iw2 = iw + kx - 1;
                if ((unsigned)iw2 >= 160u) continue;
                s16x8 vv = *(const s16x8*)&vb[((size_t)ih2 * 160 + iw2) * 96 + ch0];
#pragma unroll
                for (int e = 0; e < 8; ++e)
                    a[e] = fmaf(bf2f((unsigned short)vv[e]), lwL[(ch0 + e) * 9 + ky * 3 + kx], a[e]);
            }
        }
#pragma unroll
        for (int e = 0; e < 8; ++e) osmT[(ch0 + e) * 66 + r] += a[e];
    }
    __syncthreads();
    // store transposed: out[sb][ch][n0+r], f32x4 over r
    float* ob = out + (size_t)sb * 96 * N_ + n0;
#pragma unroll
    for (int it = 0; it < 6; ++it) {
        int qq = it * 256 + tid;
        int r4 = (qq & 15) * 4, ch = qq >> 4;
        f32x4 vv;
        vv[0] = osmT[ch * 66 + r4];
        vv[1] = osmT[ch * 66 + r4 + 1];
        vv[2] = osmT[ch * 66 + r4 + 2];
        vv[3] = osmT[ch * 66 + r4 + 3];
        *(f32x4*)&ob[(size_t)ch * N_ + r4] = vv;
    }
}

// ---------------------------------------------------------------- launch
extern "C" void kernel_launch(void* const* d_in, const int* in_sizes, int n_in,
                              void* d_out, int out_size, void* d_ws, size_t ws_size,
                              hipStream_t stream)
{
    const float* x1  = (const float*)d_in[0];
    const float* x2  = (const float*)d_in[1];
    const float* Wqk = (const float*)d_in[2];
    const float* bqk = (const float*)d_in[3];
    const float* Wv  = (const float*)d_in[4];
    const float* bv  = (const float*)d_in[5];
    const float* lw  = (const float*)d_in[6];
    const float* lb  = (const float*)d_in[7];
    float* out = (float*)d_out;

    char* ws = (char*)d_ws;
    size_t off = 0;
    auto alloc = [&](size_t bytes) -> void* {
        void* p = ws + off;
        off = (off + bytes + 255) & ~(size_t)255;
        return p;
    };
    unsigned short* qbuf = (unsigned short*)alloc(2ull * B_ * N_ * 96 * 2);
    unsigned short* vbuf = (unsigned short*)alloc(2ull * B_ * N_ * 96 * 2);
    float* kvpart = (float*)alloc(16ull * GX1 * 3072 * 4);
    float* kmpart = (float*)alloc(16ull * GX1 * 4 * 96 * 4);
    float* kvbuf  = (float*)alloc(16ull * 3072 * 4);
    float* kmbuf  = (float*)alloc(16ull * 96 * 4);
    unsigned short* wpack = (unsigned short*)alloc(3456ull * 8 * 2);
    float* csS = (float*)alloc(6720 * 4);
    float* snS = (float*)alloc(6720 * 4);

    hipLaunchKernelGGL(prep_kernel, dim3((6720 + 3456 + 255) / 256), dim3(256), 0, stream,
                       Wqk, Wv, wpack, csS, snS);
    hipLaunchKernelGGL(pass1_kernel, dim3(GX1, B_, 2), dim3(256), 0, stream,
                       x1, x2, wpack, bqk, bv, csS, snS, qbuf, vbuf, kvpart, kmpart);
    hipLaunchKernelGGL(reduce_kernel, dim3((16 * 768 + 16 * 96 + 255) / 256), dim3(256), 0, stream,
                       kvpart, kmpart, kvbuf, kmbuf);
    hipLaunchKernelGGL(pass2_kernel, dim3(NT2, B_, 2), dim3(256), 0, stream,
                       qbuf, vbuf, kvbuf, kmbuf, csS, snS, lw, lb, out);
}

// Round 21
// 193.013 us; speedup vs baseline: 1.1436x; 1.0408x over previous
//
#include <hip/hip_runtime.h>
#include <hip/hip_bf16.h>

// Problem constants (fixed by setup_inputs)
constexpr int B_ = 8;
constexpr int H_ = 120;
constexpr int W_ = 160;
constexpr int N_ = H_ * W_;     // 19200
constexpr int C_ = 96;

constexpr int GX1 = 75;         // pass1 blocks per (s,b)
constexpr int TPB1 = 4;         // tiles of 64 rows per block
constexpr int NT2 = N_ / 64;    // 300

typedef __attribute__((ext_vector_type(8))) short s16x8;
typedef __attribute__((ext_vector_type(4))) short s16x4;
typedef __attribute__((ext_vector_type(4))) float f32x4;

static __device__ inline unsigned short f2bf(float f) {
    unsigned u = __float_as_uint(f);
    return (unsigned short)((u + 0x7FFFu + ((u >> 16) & 1u)) >> 16);
}
static __device__ inline float bf2f(unsigned short h) {
    return __uint_as_float(((unsigned)h) << 16);
}
static __device__ inline void MFMA(f32x4& c, s16x8 a, s16x8 b) {
    c = __builtin_amdgcn_mfma_f32_16x16x32_bf16(a, b, c, 0, 0, 0);
}

// ---------------------------------------------------------------- prep: sincos table (6720) + W pre-pack (3456 frags)
// csS/snS layout: [0,2880): H-part (j*120+ih); [2880,6720): W-part (j*160+iw)
__global__ void prep_kernel(const float* __restrict__ Wqk, const float* __restrict__ Wv,
                            unsigned short* __restrict__ wpack,
                            float* __restrict__ csS, float* __restrict__ snS) {
    int idx = blockIdx.x * 256 + threadIdx.x;
    if (idx < 6720) {
        int j, pos;
        if (idx < 2880) { j = idx / 120; pos = idx - j * 120; }
        else { int t = idx - 2880; j = t / 160; pos = t - j * 160; }
        float theta = expf(-(float)j * (9.210340371976184f / 24.0f));
        float s, c;
        sincosf((float)pos * theta, &s, &c);
        csS[idx] = c;
        snS[idx] = s;
    } else if (idx < 6720 + 3456) {
        int i = idx - 6720;
        int s3 = i / 1152, rem = i - s3 * 1152;
        int cT = rem >> 6, lane = rem & 63;
        int col = cT * 16 + (lane & 15), k0 = s3 * 32 + 8 * (lane >> 4);
        const float* wp = (col < 192) ? (Wqk + col * 96 + k0) : (Wv + (col - 192) * 96 + k0);
        f32x4 wa = *(const f32x4*)wp;
        f32x4 wb = *(const f32x4*)(wp + 4);
        s16x8 wf;
        wf[0] = (short)f2bf(wa[0]); wf[1] = (short)f2bf(wa[1]);
        wf[2] = (short)f2bf(wa[2]); wf[3] = (short)f2bf(wa[3]);
        wf[4] = (short)f2bf(wb[0]); wf[5] = (short)f2bf(wb[1]);
        wf[6] = (short)f2bf(wb[2]); wf[7] = (short)f2bf(wb[3]);
        *(s16x8*)&wpack[i * 8] = wf;
    }
}

// ---------------------------------------------------------------- pass 1 (MFMA, fused shfl-rope, x prefetch, compact tables)
__global__ __launch_bounds__(256, 2)
void pass1_kernel(const float* __restrict__ x1, const float* __restrict__ x2,
                  const unsigned short* __restrict__ wpack,
                  const float* __restrict__ bqk, const float* __restrict__ bv,
                  const float* __restrict__ csS, const float* __restrict__ snS,
                  unsigned short* __restrict__ qbuf, unsigned short* __restrict__ vbuf,
                  float* __restrict__ kvpart, float* __restrict__ kmpart)
{
    __shared__ alignas(16) unsigned short Wl[27648];   // 55296 B, frag-order
    __shared__ alignas(16) unsigned short kTl[6144];   // 12288 B, frag-order [96ch][64r], ROPED k
    __shared__ alignas(16) unsigned short vTl[6144];   // 12288 B

    const int tid = threadIdx.x;
    const int l = tid & 63, w = tid >> 6;
    const int gx = blockIdx.x, b = blockIdx.y, s = blockIdx.z;
    const float* x = s ? x2 : x1;
    const int sb = s * B_ + b;

    // stage W from pre-packed global (coalesced, no conversion)
    for (int i = tid; i < 3456; i += 256)
        *(s16x8*)&Wl[i * 8] = *(const s16x8*)&wpack[i * 8];

    float biasv[18];
#pragma unroll
    for (int cT = 0; cT < 18; ++cT) {
        int col = cT * 16 + (l & 15);
        biasv[cT] = (col < 192) ? bqk[col] : bv[col - 192];
    }
    f32x4 kvacc[3] = {};
    float kmacc[6] = {};

    // x tile loader: 6 raw f32x4 (no conversion — keeps the prefetch pure loads)
    auto xload = [&](int n0t, f32x4* dst) {
        const float* xr = x + ((size_t)b * N_ + n0t + 16 * w + (l & 15)) * 96 + 8 * (l >> 4);
#pragma unroll
        for (int s3 = 0; s3 < 3; ++s3) {
            dst[2 * s3]     = *(const f32x4*)(xr + s3 * 32);
            dst[2 * s3 + 1] = *(const f32x4*)(xr + s3 * 32 + 4);
        }
    };
    f32x4 xcur[6], xnxt[6];
    xload(gx * TPB1 * 64, xcur);
    __syncthreads();

    for (int t = 0; t < TPB1; ++t) {
        const int n0 = (gx * TPB1 + t) * 64;
        const int r0 = 16 * w + 4 * (l >> 4);
        // prefetch next tile's x (lands during epilogue + kv-MFMA)
        if (t + 1 < TPB1) xload(n0 + 64, xnxt);
        // GEMM: wave w computes rows [16w,16w+16) x 288 cols
        f32x4 acc[18] = {};
#pragma unroll
        for (int s3 = 0; s3 < 3; ++s3) {
            f32x4 xa = xcur[2 * s3], xb = xcur[2 * s3 + 1];
            s16x8 af;
            af[0] = (short)f2bf(xa[0]); af[1] = (short)f2bf(xa[1]);
            af[2] = (short)f2bf(xa[2]); af[3] = (short)f2bf(xa[3]);
            af[4] = (short)f2bf(xb[0]); af[5] = (short)f2bf(xb[1]);
            af[6] = (short)f2bf(xb[2]); af[7] = (short)f2bf(xb[3]);
#pragma unroll
            for (int cT = 0; cT < 18; ++cT) {
                s16x8 bf = *(const s16x8*)&Wl[((s3 * 18 + cT) * 64 + l) * 8];
                MFMA(acc[cT], af, bf);
            }
        }
        // hoisted compact-table loads for THIS tile's k-epilogue.
        // rows nr..nr+3 never cross an image row (nr%4==0, 160%4==0): ih constant, iw0=nr%160
        const int nr = n0 + r0;
        const int ih = nr / 160, iw0 = nr - ih * 160;
        f32x4 c4a[6], s4a[6];
#pragma unroll
        for (int j6 = 0; j6 < 3; ++j6) {   // H-part: p = j6*8 + ((l&15)>>1) < 24, depends on ih only
            int p = j6 * 8 + ((l & 15) >> 1);
            float c = csS[p * 120 + ih], sv = snS[p * 120 + ih];
            c4a[j6][0] = c; c4a[j6][1] = c; c4a[j6][2] = c; c4a[j6][3] = c;
            s4a[j6][0] = sv; s4a[j6][1] = sv; s4a[j6][2] = sv; s4a[j6][3] = sv;
        }
#pragma unroll
        for (int j6 = 3; j6 < 6; ++j6) {   // W-part: p-24 = (j6-3)*8 + ((l&15)>>1), varies with iw
            int pw = (j6 - 3) * 8 + ((l & 15) >> 1);
            c4a[j6] = *(const f32x4*)&csS[2880 + pw * 160 + iw0];
            s4a[j6] = *(const f32x4*)&snS[2880 + pw * 160 + iw0];
        }
        __syncthreads();   // prev tile's kv-MFMA reads of kTl/vTl complete

        // ---- epilogue (rope fused via lane^1 shuffle)
        unsigned short* qb = qbuf + ((size_t)sb * N_ + n0) * 96;
        unsigned short* vb = vbuf + ((size_t)sb * N_ + n0) * 96;
#pragma unroll
        for (int cT = 0; cT < 6; ++cT) {          // q: elu+1, store pre-rope
#pragma unroll
            for (int i2 = 0; i2 < 4; ++i2) {
                float q = acc[cT][i2] + biasv[cT];
                q = (q > 0.f) ? q + 1.f : __expf(q);
                qb[(size_t)(r0 + i2) * 96 + cT * 16 + (l & 15)] = f2bf(q);
            }
        }
#pragma unroll
        for (int cT = 6; cT < 12; ++cT) {         // k: elu+1, kmean(pre-rope), rope, stage (b64)
            f32x4 c4 = c4a[cT - 6];
            f32x4 s4 = s4a[cT - 6];
            float colsum = 0.f;
            s16x4 pk;
#pragma unroll
            for (int i2 = 0; i2 < 4; ++i2) {
                float k = acc[cT][i2] + biasv[cT];
                k = (k > 0.f) ? k + 1.f : __expf(k);
                colsum += k;
                float kpart = __shfl_xor(k, 1, 64);   // partner channel (2p <-> 2p+1)
                float kr = (l & 1) ? fmaf(s4[i2], kpart, c4[i2] * k)     // odd: s*re + c*im
                                   : fmaf(-s4[i2], kpart, c4[i2] * k);   // even: c*re - s*im
                pk[i2] = (short)f2bf(kr);
            }
            int chunk = ((r0 >> 5) * 6 + (cT - 6)) * 64 + ((r0 >> 3) & 3) * 16 + (l & 15);
            *(s16x4*)&kTl[chunk * 8 + (r0 & 7)] = pk;
            colsum += __shfl_xor(colsum, 16, 64);
            colsum += __shfl_xor(colsum, 32, 64);
            kmacc[cT - 6] += colsum;
        }
#pragma unroll
        for (int cT = 12; cT < 18; ++cT) {        // v: store + stage to LDS (b64)
            s16x4 pv;
#pragma unroll
            for (int i2 = 0; i2 < 4; ++i2) {
                float v = acc[cT][i2] + biasv[cT];
                unsigned short hv = f2bf(v);
                pv[i2] = (short)hv;
                vb[(size_t)(r0 + i2) * 96 + (cT - 12) * 16 + (l & 15)] = hv;
            }
            int chunk = ((r0 >> 5) * 6 + (cT - 12)) * 64 + ((r0 >> 3) & 3) * 16 + (l & 15);
            *(s16x4*)&vTl[chunk * 8 + (r0 & 7)] = pv;
        }
        __syncthreads();
        // kv += k_roped^T @ v  (wave w owns flat C-tiles {w, w+4, w+8})
#pragma unroll
        for (int j = 0; j < 3; ++j) {
            int f = w + 4 * j;
            int h = f >> 2, dT = (f >> 1) & 1, eT = f & 1;
#pragma unroll
            for (int ks = 0; ks < 2; ++ks) {
                s16x8 a = *(const s16x8*)&kTl[(((ks * 6 + (h * 2 + dT)) << 6) + l) * 8];
                s16x8 bb = *(const s16x8*)&vTl[(((ks * 6 + (h * 2 + eT)) << 6) + l) * 8];
                MFMA(kvacc[j], a, bb);
            }
        }
        if (t + 1 < TPB1) {
#pragma unroll
            for (int i = 0; i < 6; ++i) xcur[i] = xnxt[i];
        }
    }
    // write partials
    float* kvp = kvpart + ((size_t)sb * GX1 + gx) * 3072;
#pragma unroll
    for (int j = 0; j < 3; ++j) {
        int f = w + 4 * j;
        int h = f >> 2, dT = (f >> 1) & 1, eT = f & 1;
#pragma unroll
        for (int i2 = 0; i2 < 4; ++i2)
            kvp[h * 1024 + (dT * 16 + 4 * (l >> 4) + i2) * 32 + eT * 16 + (l & 15)] = kvacc[j][i2];
    }
    if (l < 16) {
        float* kmp = kmpart + ((size_t)((size_t)sb * GX1 + gx) * 4 + w) * 96;
#pragma unroll
        for (int j6 = 0; j6 < 6; ++j6) kmp[j6 * 16 + l] = kmacc[j6];
    }
}

// ---------------------------------------------------------------- reduce (kv -> bf16 TRANSPOSED [h][e][d])
__global__ void reduce_kernel(const float* __restrict__ kvpart, const float* __restrict__ kmpart,
                              unsigned short* __restrict__ kvT, float* __restrict__ kmbuf)
{
    int idx = blockIdx.x * 256 + threadIdx.x;
    const float invN = 1.0f / (float)N_;
    if (idx < 16 * 768) {
        // thread = (sb, h, d4, e): sums 4 d-rows at fixed e, writes d-contiguous bf16x4 transposed
        int sb = idx / 768, r = idx - sb * 768;
        int h = r >> 8, d4 = (r >> 5) & 7, e = r & 31;
        float a0 = 0.f, a1 = 0.f, a2 = 0.f, a3 = 0.f;
        const float* src = kvpart + (size_t)sb * GX1 * 3072 + h * 1024 + e;
        for (int g = 0; g < GX1; ++g) {
            const float* p = src + (size_t)g * 3072 + d4 * 128;
            a0 += p[0]; a1 += p[32]; a2 += p[64]; a3 += p[96];
        }
        s16x4 o;
        o[0] = (short)f2bf(a0 * invN); o[1] = (short)f2bf(a1 * invN);
        o[2] = (short)f2bf(a2 * invN); o[3] = (short)f2bf(a3 * invN);
        *(s16x4*)&kvT[(size_t)sb * 3072 + (h * 32 + e) * 32 + d4 * 4] = o;
    } else if (idx < 16 * 768 + 16 * 96) {
        int j = idx - 16 * 768;
        int sb = j / 96, ch = j - sb * 96;
        float acc = 0.f;
        for (int g = 0; g < GX1 * 4; ++g) acc += kmpart[((size_t)sb * GX1 * 4 + g) * 96 + ch];
        kmbuf[j] = acc * invN;
    }
}

// ---------------------------------------------------------------- pass 2 (no kv staging: direct bf16 kvT frags, shfl-z, 2 barriers)
__global__ __launch_bounds__(256, 5)
void pass2_kernel(const unsigned short* __restrict__ qbuf, const unsigned short* __restrict__ vbuf,
                  const unsigned short* __restrict__ kvT, const float* __restrict__ kmbuf,
                  const float* __restrict__ csS, const float* __restrict__ snS,
                  const float* __restrict__ lw, const float* __restrict__ lb,
                  float* __restrict__ out)
{
    __shared__ alignas(16) float osmT[96 * 66];   // 25344 B
    __shared__ float lwL[864], lbL[96];

    const int tid = threadIdx.x, l = tid & 63, w = tid >> 6;
    // XCD-bijective tile swizzle (nwg=300: q=37, r=4) — contiguous tile runs per XCD for conv-halo L2 reuse
    const int orig = blockIdx.x;
    const int xcd = orig & 7, i8 = orig >> 3;
    const int tile = (xcd < 4 ? xcd * 38 : 152 + (xcd - 4) * 37) + i8;
    const int b = blockIdx.y, s = blockIdx.z, so = 1 - s;
    const int n0 = tile * 64;
    const int sb = s * B_ + b, sbo = so * B_ + b;

    for (int i = tid; i < 864; i += 256) lwL[i] = lw[i];
    if (tid < 96) lbL[tid] = lb[tid];

    // per-lane q fragment loads (direct from global)
    const int qrow = n0 + 16 * w + (l & 15);
    const int ihq = qrow / 160, iwq = qrow - ihq * 160;
    const unsigned short* qr = qbuf + ((size_t)sb * N_ + qrow) * 96 + 8 * (l >> 4);
    const float* kmp = kmbuf + (size_t)sbo * 96 + 8 * (l >> 4);
    s16x8 qf[3];
    float zinv[3];
#pragma unroll
    for (int h = 0; h < 3; ++h) {
        qf[h] = *(const s16x8*)&qr[h * 32];
        f32x4 km0 = *(const f32x4*)&kmp[h * 32];
        f32x4 km1 = *(const f32x4*)&kmp[h * 32 + 4];
        float zp = 0.f;
#pragma unroll
        for (int e = 0; e < 4; ++e) zp += bf2f((unsigned short)qf[h][e]) * km0[e];
#pragma unroll
        for (int e = 0; e < 4; ++e) zp += bf2f((unsigned short)qf[h][4 + e]) * km1[e];
        zp += __shfl_xor(zp, 16, 64);
        zp += __shfl_xor(zp, 32, 64);
        zinv[h] = 1.f / (zp + 1e-6f);   // lanes with same (l&15) hold z for row 16w+(l&15)
    }
    // rope q in registers: pairs (2j,2j+1) within the lane's 8-elem chunk; compact table
    s16x8 af[3];
#pragma unroll
    for (int h = 0; h < 3; ++h) {
#pragma unroll
        for (int j = 0; j < 4; ++j) {
            int p = h * 16 + 4 * (l >> 4) + j;
            float c, sv;
            if (p < 24) { c = csS[p * 120 + ihq]; sv = snS[p * 120 + ihq]; }
            else { c = csS[2880 + (p - 24) * 160 + iwq]; sv = snS[2880 + (p - 24) * 160 + iwq]; }
            float re = bf2f((unsigned short)qf[h][2 * j]);
            float im = bf2f((unsigned short)qf[h][2 * j + 1]);
            af[h][2 * j]     = (short)f2bf(c * re - sv * im);
            af[h][2 * j + 1] = (short)f2bf(sv * re + c * im);
        }
    }
    // o = rope(q) @ kv — B fragments direct from transposed bf16 kvT (L2-hot, 12 KB/(s,b))
    const unsigned short* kvb = kvT + (size_t)sbo * 3072;
    f32x4 oac[3][2] = {};
#pragma unroll
    for (int h = 0; h < 3; ++h) {
#pragma unroll
        for (int eT = 0; eT < 2; ++eT) {
            s16x8 bfr = *(const s16x8*)&kvb[(h * 32 + eT * 16 + (l & 15)) * 32 + 8 * (l >> 4)];
            MFMA(oac[h][eT], af[h], bfr);
        }
    }
    // scale by z (fetched intra-wave via shfl) and write transposed to osmT
#pragma unroll
    for (int h = 0; h < 3; ++h) {
#pragma unroll
        for (int i2 = 0; i2 < 4; ++i2) {
            int row = 16 * w + 4 * (l >> 4) + i2;
            float z = __shfl(zinv[h], 4 * (l >> 4) + i2, 64);
            osmT[(h * 32 + (l & 15)) * 66 + row] = oac[h][0][i2] * z;
            osmT[(h * 32 + 16 + (l & 15)) * 66 + row] = oac[h][1][i2] * z;
        }
    }
    __syncthreads();
    // LePE conv add: 768 ch-octets (64 r x 12 octets), ch-fast, u16x8 loads
    const unsigned short* vb = vbuf + (size_t)sb * (size_t)N_ * 96;
#pragma unroll
    for (int it = 0; it < 3; ++it) {
        int oct = it * 256 + tid;
        int r = oct / 12, c8 = oct - r * 12;
        int ch0 = c8 * 8;
        int npos = n0 + r, ih = npos / 160, iw = npos - ih * 160;
        float a[8];
#pragma unroll
        for (int e = 0; e < 8; ++e) a[e] = lbL[ch0 + e];
#pragma unroll
        for (int ky = 0; ky < 3; ++ky) {
            int ih2 = ih + ky - 1;
            if ((unsigned)ih2 >= 120u) continue;
#pragma unroll
            for (int kx = 0; kx < 3; ++kx) {
                int iw2 = iw + kx - 1;
                if ((unsigned)iw2 >= 160u) continue;
                s16x8 vv = *(const s16x8*)&vb[((size_t)ih2 * 160 + iw2) * 96 + ch0];
#pragma unroll
                for (int e = 0; e < 8; ++e)
                    a[e] = fmaf(bf2f((unsigned short)vv[e]), lwL[(ch0 + e) * 9 + ky * 3 + kx], a[e]);
            }
        }
#pragma unroll
        for (int e = 0; e < 8; ++e) osmT[(ch0 + e) * 66 + r] += a[e];
    }
    __syncthreads();
    // store transposed: out[sb][ch][n0+r], f32x4 over r
    float* ob = out + (size_t)sb * 96 * N_ + n0;
#pragma unroll
    for (int it = 0; it < 6; ++it) {
        int qq = it * 256 + tid;
        int r4 = (qq & 15) * 4, ch = qq >> 4;
        f32x4 vv;
        vv[0] = osmT[ch * 66 + r4];
        vv[1] = osmT[ch * 66 + r4 + 1];
        vv[2] = osmT[ch * 66 + r4 + 2];
        vv[3] = osmT[ch * 66 + r4 + 3];
        *(f32x4*)&ob[(size_t)ch * N_ + r4] = vv;
    }
}

// ---------------------------------------------------------------- launch
extern "C" void kernel_launch(void* const* d_in, const int* in_sizes, int n_in,
                              void* d_out, int out_size, void* d_ws, size_t ws_size,
                              hipStream_t stream)
{
    const float* x1  = (const float*)d_in[0];
    const float* x2  = (const float*)d_in[1];
    const float* Wqk = (const float*)d_in[2];
    const float* bqk = (const float*)d_in[3];
    const float* Wv  = (const float*)d_in[4];
    const float* bv  = (const float*)d_in[5];
    const float* lw  = (const float*)d_in[6];
    const float* lb  = (const float*)d_in[7];
    float* out = (float*)d_out;

    char* ws = (char*)d_ws;
    size_t off = 0;
    auto alloc = [&](size_t bytes) -> void* {
        void* p = ws + off;
        off = (off + bytes + 255) & ~(size_t)255;
        return p;
    };
    unsigned short* qbuf = (unsigned short*)alloc(2ull * B_ * N_ * 96 * 2);
    unsigned short* vbuf = (unsigned short*)alloc(2ull * B_ * N_ * 96 * 2);
    float* kvpart = (float*)alloc(16ull * GX1 * 3072 * 4);
    float* kmpart = (float*)alloc(16ull * GX1 * 4 * 96 * 4);
    unsigned short* kvT = (unsigned short*)alloc(16ull * 3072 * 2);
    float* kmbuf  = (float*)alloc(16ull * 96 * 4);
    unsigned short* wpack = (unsigned short*)alloc(3456ull * 8 * 2);
    float* csS = (float*)alloc(6720 * 4);
    float* snS = (float*)alloc(6720 * 4);

    hipLaunchKernelGGL(prep_kernel, dim3((6720 + 3456 + 255) / 256), dim3(256), 0, stream,
                       Wqk, Wv, wpack, csS, snS);
    hipLaunchKernelGGL(pass1_kernel, dim3(GX1, B_, 2), dim3(256), 0, stream,
                       x1, x2, wpack, bqk, bv, csS, snS, qbuf, vbuf, kvpart, kmpart);
    hipLaunchKernelGGL(reduce_kernel, dim3((16 * 768 + 16 * 96 + 255) / 256), dim3(256), 0, stream,
                       kvpart, kmpart, kvT, kmbuf);
    hipLaunchKernelGGL(pass2_kernel, dim3(NT2, B_, 2), dim3(256), 0, stream,
                       qbuf, vbuf, kvT, kmbuf, csS, snS, lw, lb, out);
}

// Round 22
// 179.522 us; speedup vs baseline: 1.2295x; 1.0752x over previous
//
#include <hip/hip_runtime.h>
#include <hip/hip_bf16.h>

// Problem constants (fixed by setup_inputs)
constexpr int B_ = 8;
constexpr int H_ = 120;
constexpr int W_ = 160;
constexpr int N_ = H_ * W_;     // 19200
constexpr int C_ = 96;

constexpr int GX1 = 75;         // pass1 blocks per (s,b)
constexpr int TPB1 = 4;         // tiles of 64 rows per block
constexpr int NT2 = N_ / 64;    // 300

typedef __attribute__((ext_vector_type(8))) short s16x8;
typedef __attribute__((ext_vector_type(4))) short s16x4;
typedef __attribute__((ext_vector_type(4))) float f32x4;

static __device__ inline unsigned short f2bf(float f) {
    unsigned u = __float_as_uint(f);
    return (unsigned short)((u + 0x7FFFu + ((u >> 16) & 1u)) >> 16);
}
static __device__ inline float bf2f(unsigned short h) {
    return __uint_as_float(((unsigned)h) << 16);
}
static __device__ inline void MFMA(f32x4& c, s16x8 a, s16x8 b) {
    c = __builtin_amdgcn_mfma_f32_16x16x32_bf16(a, b, c, 0, 0, 0);
}

// ---------------------------------------------------------------- prep: sincos table (6720) + W pre-pack (3456 frags)
// csS/snS layout: [0,2880): H-part (j*120+ih); [2880,6720): W-part (j*160+iw)
__global__ void prep_kernel(const float* __restrict__ Wqk, const float* __restrict__ Wv,
                            unsigned short* __restrict__ wpack,
                            float* __restrict__ csS, float* __restrict__ snS) {
    int idx = blockIdx.x * 256 + threadIdx.x;
    if (idx < 6720) {
        int j, pos;
        if (idx < 2880) { j = idx / 120; pos = idx - j * 120; }
        else { int t = idx - 2880; j = t / 160; pos = t - j * 160; }
        float theta = expf(-(float)j * (9.210340371976184f / 24.0f));
        float s, c;
        sincosf((float)pos * theta, &s, &c);
        csS[idx] = c;
        snS[idx] = s;
    } else if (idx < 6720 + 3456) {
        int i = idx - 6720;
        int s3 = i / 1152, rem = i - s3 * 1152;
        int cT = rem >> 6, lane = rem & 63;
        int col = cT * 16 + (lane & 15), k0 = s3 * 32 + 8 * (lane >> 4);
        const float* wp = (col < 192) ? (Wqk + col * 96 + k0) : (Wv + (col - 192) * 96 + k0);
        f32x4 wa = *(const f32x4*)wp;
        f32x4 wb = *(const f32x4*)(wp + 4);
        s16x8 wf;
        wf[0] = (short)f2bf(wa[0]); wf[1] = (short)f2bf(wa[1]);
        wf[2] = (short)f2bf(wa[2]); wf[3] = (short)f2bf(wa[3]);
        wf[4] = (short)f2bf(wb[0]); wf[5] = (short)f2bf(wb[1]);
        wf[6] = (short)f2bf(wb[2]); wf[7] = (short)f2bf(wb[3]);
        *(s16x8*)&wpack[i * 8] = wf;
    }
}

// ---------------------------------------------------------------- pass 1 (MFMA, fused shfl-rope, x prefetch, compact tables)
__global__ __launch_bounds__(256, 2)
void pass1_kernel(const float* __restrict__ x1, const float* __restrict__ x2,
                  const unsigned short* __restrict__ wpack,
                  const float* __restrict__ bqk, const float* __restrict__ bv,
                  const float* __restrict__ csS, const float* __restrict__ snS,
                  unsigned short* __restrict__ qbuf, unsigned short* __restrict__ vbuf,
                  float* __restrict__ kvpart, float* __restrict__ kmpart)
{
    __shared__ alignas(16) unsigned short Wl[27648];   // 55296 B, frag-order
    __shared__ alignas(16) unsigned short kTl[6144];   // 12288 B, frag-order [96ch][64r], ROPED k
    __shared__ alignas(16) unsigned short vTl[6144];   // 12288 B

    const int tid = threadIdx.x;
    const int l = tid & 63, w = tid >> 6;
    const int gx = blockIdx.x, b = blockIdx.y, s = blockIdx.z;
    const float* x = s ? x2 : x1;
    const int sb = s * B_ + b;

    // stage W from pre-packed global (coalesced, no conversion)
    for (int i = tid; i < 3456; i += 256)
        *(s16x8*)&Wl[i * 8] = *(const s16x8*)&wpack[i * 8];

    float biasv[18];
#pragma unroll
    for (int cT = 0; cT < 18; ++cT) {
        int col = cT * 16 + (l & 15);
        biasv[cT] = (col < 192) ? bqk[col] : bv[col - 192];
    }
    f32x4 kvacc[3] = {};
    float kmacc[6] = {};

    // x tile loader: 6 raw f32x4 (no conversion — keeps the prefetch pure loads)
    auto xload = [&](int n0t, f32x4* dst) {
        const float* xr = x + ((size_t)b * N_ + n0t + 16 * w + (l & 15)) * 96 + 8 * (l >> 4);
#pragma unroll
        for (int s3 = 0; s3 < 3; ++s3) {
            dst[2 * s3]     = *(const f32x4*)(xr + s3 * 32);
            dst[2 * s3 + 1] = *(const f32x4*)(xr + s3 * 32 + 4);
        }
    };
    f32x4 xcur[6], xnxt[6];
    xload(gx * TPB1 * 64, xcur);
    __syncthreads();

    for (int t = 0; t < TPB1; ++t) {
        const int n0 = (gx * TPB1 + t) * 64;
        const int r0 = 16 * w + 4 * (l >> 4);
        // prefetch next tile's x (lands during epilogue + kv-MFMA)
        if (t + 1 < TPB1) xload(n0 + 64, xnxt);
        // GEMM: wave w computes rows [16w,16w+16) x 288 cols
        f32x4 acc[18] = {};
#pragma unroll
        for (int s3 = 0; s3 < 3; ++s3) {
            f32x4 xa = xcur[2 * s3], xb = xcur[2 * s3 + 1];
            s16x8 af;
            af[0] = (short)f2bf(xa[0]); af[1] = (short)f2bf(xa[1]);
            af[2] = (short)f2bf(xa[2]); af[3] = (short)f2bf(xa[3]);
            af[4] = (short)f2bf(xb[0]); af[5] = (short)f2bf(xb[1]);
            af[6] = (short)f2bf(xb[2]); af[7] = (short)f2bf(xb[3]);
#pragma unroll
            for (int cT = 0; cT < 18; ++cT) {
                s16x8 bf = *(const s16x8*)&Wl[((s3 * 18 + cT) * 64 + l) * 8];
                MFMA(acc[cT], af, bf);
            }
        }
        // hoisted compact-table loads for THIS tile's k-epilogue.
        // rows nr..nr+3 never cross an image row (nr%4==0, 160%4==0): ih constant, iw0=nr%160
        const int nr = n0 + r0;
        const int ih = nr / 160, iw0 = nr - ih * 160;
        f32x4 c4a[6], s4a[6];
#pragma unroll
        for (int j6 = 0; j6 < 3; ++j6) {   // H-part: p = j6*8 + ((l&15)>>1) < 24, depends on ih only
            int p = j6 * 8 + ((l & 15) >> 1);
            float c = csS[p * 120 + ih], sv = snS[p * 120 + ih];
            c4a[j6][0] = c; c4a[j6][1] = c; c4a[j6][2] = c; c4a[j6][3] = c;
            s4a[j6][0] = sv; s4a[j6][1] = sv; s4a[j6][2] = sv; s4a[j6][3] = sv;
        }
#pragma unroll
        for (int j6 = 3; j6 < 6; ++j6) {   // W-part: p-24 = (j6-3)*8 + ((l&15)>>1), varies with iw
            int pw = (j6 - 3) * 8 + ((l & 15) >> 1);
            c4a[j6] = *(const f32x4*)&csS[2880 + pw * 160 + iw0];
            s4a[j6] = *(const f32x4*)&snS[2880 + pw * 160 + iw0];
        }
        __syncthreads();   // prev tile's kv-MFMA reads of kTl/vTl complete

        // ---- epilogue (rope fused via lane^1 shuffle)
        unsigned short* qb = qbuf + ((size_t)sb * N_ + n0) * 96;
        unsigned short* vb = vbuf + ((size_t)sb * N_ + n0) * 96;
#pragma unroll
        for (int cT = 0; cT < 6; ++cT) {          // q: elu+1, store pre-rope
#pragma unroll
            for (int i2 = 0; i2 < 4; ++i2) {
                float q = acc[cT][i2] + biasv[cT];
                q = (q > 0.f) ? q + 1.f : __expf(q);
                qb[(size_t)(r0 + i2) * 96 + cT * 16 + (l & 15)] = f2bf(q);
            }
        }
#pragma unroll
        for (int cT = 6; cT < 12; ++cT) {         // k: elu+1, kmean(pre-rope), rope, stage (b64)
            f32x4 c4 = c4a[cT - 6];
            f32x4 s4 = s4a[cT - 6];
            float colsum = 0.f;
            s16x4 pk;
#pragma unroll
            for (int i2 = 0; i2 < 4; ++i2) {
                float k = acc[cT][i2] + biasv[cT];
                k = (k > 0.f) ? k + 1.f : __expf(k);
                colsum += k;
                float kpart = __shfl_xor(k, 1, 64);   // partner channel (2p <-> 2p+1)
                float kr = (l & 1) ? fmaf(s4[i2], kpart, c4[i2] * k)     // odd: s*re + c*im
                                   : fmaf(-s4[i2], kpart, c4[i2] * k);   // even: c*re - s*im
                pk[i2] = (short)f2bf(kr);
            }
            int chunk = ((r0 >> 5) * 6 + (cT - 6)) * 64 + ((r0 >> 3) & 3) * 16 + (l & 15);
            *(s16x4*)&kTl[chunk * 8 + (r0 & 7)] = pk;
            colsum += __shfl_xor(colsum, 16, 64);
            colsum += __shfl_xor(colsum, 32, 64);
            kmacc[cT - 6] += colsum;
        }
#pragma unroll
        for (int cT = 12; cT < 18; ++cT) {        // v: store + stage to LDS (b64)
            s16x4 pv;
#pragma unroll
            for (int i2 = 0; i2 < 4; ++i2) {
                float v = acc[cT][i2] + biasv[cT];
                unsigned short hv = f2bf(v);
                pv[i2] = (short)hv;
                vb[(size_t)(r0 + i2) * 96 + (cT - 12) * 16 + (l & 15)] = hv;
            }
            int chunk = ((r0 >> 5) * 6 + (cT - 12)) * 64 + ((r0 >> 3) & 3) * 16 + (l & 15);
            *(s16x4*)&vTl[chunk * 8 + (r0 & 7)] = pv;
        }
        __syncthreads();
        // kv += k_roped^T @ v  (wave w owns flat C-tiles {w, w+4, w+8})
#pragma unroll
        for (int j = 0; j < 3; ++j) {
            int f = w + 4 * j;
            int h = f >> 2, dT = (f >> 1) & 1, eT = f & 1;
#pragma unroll
            for (int ks = 0; ks < 2; ++ks) {
                s16x8 a = *(const s16x8*)&kTl[(((ks * 6 + (h * 2 + dT)) << 6) + l) * 8];
                s16x8 bb = *(const s16x8*)&vTl[(((ks * 6 + (h * 2 + eT)) << 6) + l) * 8];
                MFMA(kvacc[j], a, bb);
            }
        }
        if (t + 1 < TPB1) {
#pragma unroll
            for (int i = 0; i < 6; ++i) xcur[i] = xnxt[i];
        }
    }
    // write partials
    float* kvp = kvpart + ((size_t)sb * GX1 + gx) * 3072;
#pragma unroll
    for (int j = 0; j < 3; ++j) {
        int f = w + 4 * j;
        int h = f >> 2, dT = (f >> 1) & 1, eT = f & 1;
#pragma unroll
        for (int i2 = 0; i2 < 4; ++i2)
            kvp[h * 1024 + (dT * 16 + 4 * (l >> 4) + i2) * 32 + eT * 16 + (l & 15)] = kvacc[j][i2];
    }
    if (l < 16) {
        float* kmp = kmpart + ((size_t)((size_t)sb * GX1 + gx) * 4 + w) * 96;
#pragma unroll
        for (int j6 = 0; j6 < 6; ++j6) kmp[j6 * 16 + l] = kmacc[j6];
    }
}

// ---------------------------------------------------------------- reduce (kv -> bf16 TRANSPOSED [h][e][d])
__global__ void reduce_kernel(const float* __restrict__ kvpart, const float* __restrict__ kmpart,
                              unsigned short* __restrict__ kvT, float* __restrict__ kmbuf)
{
    int idx = blockIdx.x * 256 + threadIdx.x;
    const float invN = 1.0f / (float)N_;
    if (idx < 16 * 768) {
        // thread = (sb, h, d4, e): sums 4 d-rows at fixed e, writes d-contiguous bf16x4 transposed
        int sb = idx / 768, r = idx - sb * 768;
        int h = r >> 8, d4 = (r >> 5) & 7, e = r & 31;
        float a0 = 0.f, a1 = 0.f, a2 = 0.f, a3 = 0.f;
        const float* src = kvpart + (size_t)sb * GX1 * 3072 + h * 1024 + e;
        for (int g = 0; g < GX1; ++g) {
            const float* p = src + (size_t)g * 3072 + d4 * 128;
            a0 += p[0]; a1 += p[32]; a2 += p[64]; a3 += p[96];
        }
        s16x4 o;
        o[0] = (short)f2bf(a0 * invN); o[1] = (short)f2bf(a1 * invN);
        o[2] = (short)f2bf(a2 * invN); o[3] = (short)f2bf(a3 * invN);
        *(s16x4*)&kvT[(size_t)sb * 3072 + (h * 32 + e) * 32 + d4 * 4] = o;
    } else if (idx < 16 * 768 + 16 * 96) {
        int j = idx - 16 * 768;
        int sb = j / 96, ch = j - sb * 96;
        float acc = 0.f;
        for (int g = 0; g < GX1 * 4; ++g) acc += kmpart[((size_t)sb * GX1 * 4 + g) * 96 + ch];
        kmbuf[j] = acc * invN;
    }
}

// ---------------------------------------------------------------- pass 2 (no kv staging, shfl-z, transposed conv weights)
__global__ __launch_bounds__(256, 5)
void pass2_kernel(const unsigned short* __restrict__ qbuf, const unsigned short* __restrict__ vbuf,
                  const unsigned short* __restrict__ kvT, const float* __restrict__ kmbuf,
                  const float* __restrict__ csS, const float* __restrict__ snS,
                  const float* __restrict__ lw, const float* __restrict__ lb,
                  float* __restrict__ out)
{
    __shared__ alignas(16) float osmT[96 * 66];   // 25344 B
    __shared__ alignas(16) float lwT[864];        // TRANSPOSED [tap][ch]: vectorizable weight fetch
    __shared__ float lbL[96];

    const int tid = threadIdx.x, l = tid & 63, w = tid >> 6;
    // XCD-bijective tile swizzle (nwg=300: q=37, r=4) — contiguous tile runs per XCD for conv-halo L2 reuse
    const int orig = blockIdx.x;
    const int xcd = orig & 7, i8 = orig >> 3;
    const int tile = (xcd < 4 ? xcd * 38 : 152 + (xcd - 4) * 37) + i8;
    const int b = blockIdx.y, s = blockIdx.z, so = 1 - s;
    const int n0 = tile * 64;
    const int sb = s * B_ + b, sbo = so * B_ + b;

    for (int i = tid; i < 864; i += 256) lwT[i] = lw[(i % 96) * 9 + i / 96];
    if (tid < 96) lbL[tid] = lb[tid];

    // per-lane q fragment loads (direct from global)
    const int qrow = n0 + 16 * w + (l & 15);
    const int ihq = qrow / 160, iwq = qrow - ihq * 160;
    const unsigned short* qr = qbuf + ((size_t)sb * N_ + qrow) * 96 + 8 * (l >> 4);
    const float* kmp = kmbuf + (size_t)sbo * 96 + 8 * (l >> 4);
    s16x8 qf[3];
    float zinv[3];
#pragma unroll
    for (int h = 0; h < 3; ++h) {
        qf[h] = *(const s16x8*)&qr[h * 32];
        f32x4 km0 = *(const f32x4*)&kmp[h * 32];
        f32x4 km1 = *(const f32x4*)&kmp[h * 32 + 4];
        float zp = 0.f;
#pragma unroll
        for (int e = 0; e < 4; ++e) zp += bf2f((unsigned short)qf[h][e]) * km0[e];
#pragma unroll
        for (int e = 0; e < 4; ++e) zp += bf2f((unsigned short)qf[h][4 + e]) * km1[e];
        zp += __shfl_xor(zp, 16, 64);
        zp += __shfl_xor(zp, 32, 64);
        zinv[h] = 1.f / (zp + 1e-6f);   // lanes with same (l&15) hold z for row 16w+(l&15)
    }
    // rope q in registers: pairs (2j,2j+1) within the lane's 8-elem chunk; compact table
    s16x8 af[3];
#pragma unroll
    for (int h = 0; h < 3; ++h) {
#pragma unroll
        for (int j = 0; j < 4; ++j) {
            int p = h * 16 + 4 * (l >> 4) + j;
            float c, sv;
            if (p < 24) { c = csS[p * 120 + ihq]; sv = snS[p * 120 + ihq]; }
            else { c = csS[2880 + (p - 24) * 160 + iwq]; sv = snS[2880 + (p - 24) * 160 + iwq]; }
            float re = bf2f((unsigned short)qf[h][2 * j]);
            float im = bf2f((unsigned short)qf[h][2 * j + 1]);
            af[h][2 * j]     = (short)f2bf(c * re - sv * im);
            af[h][2 * j + 1] = (short)f2bf(sv * re + c * im);
        }
    }
    // o = rope(q) @ kv — B fragments direct from transposed bf16 kvT (L2-hot, 12 KB/(s,b))
    const unsigned short* kvb = kvT + (size_t)sbo * 3072;
    f32x4 oac[3][2] = {};
#pragma unroll
    for (int h = 0; h < 3; ++h) {
#pragma unroll
        for (int eT = 0; eT < 2; ++eT) {
            s16x8 bfr = *(const s16x8*)&kvb[(h * 32 + eT * 16 + (l & 15)) * 32 + 8 * (l >> 4)];
            MFMA(oac[h][eT], af[h], bfr);
        }
    }
    // scale by z (fetched intra-wave via shfl) and write transposed to osmT
#pragma unroll
    for (int h = 0; h < 3; ++h) {
#pragma unroll
        for (int i2 = 0; i2 < 4; ++i2) {
            int row = 16 * w + 4 * (l >> 4) + i2;
            float z = __shfl(zinv[h], 4 * (l >> 4) + i2, 64);
            osmT[(h * 32 + (l & 15)) * 66 + row] = oac[h][0][i2] * z;
            osmT[(h * 32 + 16 + (l & 15)) * 66 + row] = oac[h][1][i2] * z;
        }
    }
    __syncthreads();
    // LePE conv add: 768 ch-octets (64 r x 12 octets), ch-fast, u16x8 loads,
    // vectorized weight fetch from lwT (2x f32x4 per tap instead of 8 scalar)
    const unsigned short* vb = vbuf + (size_t)sb * (size_t)N_ * 96;
#pragma unroll
    for (int it = 0; it < 3; ++it) {
        int oct = it * 256 + tid;
        int r = oct / 12, c8 = oct - r * 12;
        int ch0 = c8 * 8;
        int npos = n0 + r, ih = npos / 160, iw = npos - ih * 160;
        float a[8];
#pragma unroll
        for (int e = 0; e < 8; ++e) a[e] = lbL[ch0 + e];
#pragma unroll
        for (int ky = 0; ky < 3; ++ky) {
            int ih2 = ih + ky - 1;
            if ((unsigned)ih2 >= 120u) continue;
#pragma unroll
            for (int kx = 0; kx < 3; ++kx) {
                int iw2 = iw + kx - 1;
                if ((unsigned)iw2 >= 160u) continue;
                s16x8 vv = *(const s16x8*)&vb[((size_t)ih2 * 160 + iw2) * 96 + ch0];
                int t9 = ky * 3 + kx;
                f32x4 wa = *(const f32x4*)&lwT[t9 * 96 + ch0];
                f32x4 wb = *(const f32x4*)&lwT[t9 * 96 + ch0 + 4];
#pragma unroll
                for (int e = 0; e < 4; ++e)
                    a[e] = fmaf(bf2f((unsigned short)vv[e]), wa[e], a[e]);
#pragma unroll
                for (int e = 0; e < 4; ++e)
                    a[4 + e] = fmaf(bf2f((unsigned short)vv[4 + e]), wb[e], a[4 + e]);
            }
        }
#pragma unroll
        for (int e = 0; e < 8; ++e) osmT[(ch0 + e) * 66 + r] += a[e];
    }
    __syncthreads();
    // store transposed: out[sb][ch][n0+r], f32x4 over r
    float* ob = out + (size_t)sb * 96 * N_ + n0;
#pragma unroll
    for (int it = 0; it < 6; ++it) {
        int qq = it * 256 + tid;
        int r4 = (qq & 15) * 4, ch = qq >> 4;
        f32x4 vv;
        vv[0] = osmT[ch * 66 + r4];
        vv[1] = osmT[ch * 66 + r4 + 1];
        vv[2] = osmT[ch * 66 + r4 + 2];
        vv[3] = osmT[ch * 66 + r4 + 3];
        *(f32x4*)&ob[(size_t)ch * N_ + r4] = vv;
    }
}

// ---------------------------------------------------------------- launch
extern "C" void kernel_launch(void* const* d_in, const int* in_sizes, int n_in,
                              void* d_out, int out_size, void* d_ws, size_t ws_size,
                              hipStream_t stream)
{
    const float* x1  = (const float*)d_in[0];
    const float* x2  = (const float*)d_in[1];
    const float* Wqk = (const float*)d_in[2];
    const float* bqk = (const float*)d_in[3];
    const float* Wv  = (const float*)d_in[4];
    const float* bv  = (const float*)d_in[5];
    const float* lw  = (const float*)d_in[6];
    const float* lb  = (const float*)d_in[7];
    float* out = (float*)d_out;

    char* ws = (char*)d_ws;
    size_t off = 0;
    auto alloc = [&](size_t bytes) -> void* {
        void* p = ws + off;
        off = (off + bytes + 255) & ~(size_t)255;
        return p;
    };
    unsigned short* qbuf = (unsigned short*)alloc(2ull * B_ * N_ * 96 * 2);
    unsigned short* vbuf = (unsigned short*)alloc(2ull * B_ * N_ * 96 * 2);
    float* kvpart = (float*)alloc(16ull * GX1 * 3072 * 4);
    float* kmpart = (float*)alloc(16ull * GX1 * 4 * 96 * 4);
    unsigned short* kvT = (unsigned short*)alloc(16ull * 3072 * 2);
    float* kmbuf  = (float*)alloc(16ull * 96 * 4);
    unsigned short* wpack = (unsigned short*)alloc(3456ull * 8 * 2);
    float* csS = (float*)alloc(6720 * 4);
    float* snS = (float*)alloc(6720 * 4);

    hipLaunchKernelGGL(prep_kernel, dim3((6720 + 3456 + 255) / 256), dim3(256), 0, stream,
                       Wqk, Wv, wpack, csS, snS);
    hipLaunchKernelGGL(pass1_kernel, dim3(GX1, B_, 2), dim3(256), 0, stream,
                       x1, x2, wpack, bqk, bv, csS, snS, qbuf, vbuf, kvpart, kmpart);
    hipLaunchKernelGGL(reduce_kernel, dim3((16 * 768 + 16 * 96 + 255) / 256), dim3(256), 0, stream,
                       kvpart, kmpart, kvT, kmbuf);
    hipLaunchKernelGGL(pass2_kernel, dim3(NT2, B_, 2), dim3(256), 0, stream,
                       qbuf, vbuf, kvT, kmbuf, csS, snS, lw, lb, out);
}